// Round 8
// baseline (183.705 us; speedup 1.0000x reference)
//
#include <hip/hip_runtime.h>
#include <math.h>

#define D_INNER 5120
#define DT_RANK 160
#define N_STATE 16
#define BATCH   256
#define KTOT    192               // 160 (dt_low) | 16 (B) | 16 (C)

// ---- K1 config: 256-thr blocks, 4 waves x 40-dd chunks, intra-block reduce ----
#define BGRP    8                 // batches per block
#define NBG     (BATCH / BGRP)    // 32
#define DDBLK   160               // dd per block (4 waves x 40)
#define NDDB    (D_INNER / DDBLK) // 32 -> SPLIT partials
#define SPLIT   32

// ---- K3 config: 1-wave blocks, 4 batches/block, 5120 blocks (20/CU queued) ----
#define K3_BT   4

// ---- workspace layout (float offsets) ----
#define OFF_T     0
#define SZ_T      (BATCH * KTOT)                  // 49,152
#define OFF_P     (OFF_T + SZ_T)
#define SZ_P      (SPLIT * BATCH * KTOT)          // 1,572,864 (6.3 MB)

// ---------------------------------------------------------------------------
// K1: projection GEMM partials (unchanged, ~10 us).
// ---------------------------------------------------------------------------
__global__ __launch_bounds__(256) void k1_gemm(const float* __restrict__ x,
                                               const float* __restrict__ Wdtlow,
                                               const float* __restrict__ WB,
                                               const float* __restrict__ WC,
                                               float* __restrict__ ws) {
    __shared__ float lds[4 * BGRP * KTOT];   // 6144 floats = 24 KB
    const int tid  = threadIdx.x;
    const int lane = tid & 63;
    const int wv   = tid >> 6;               // wave 0..3
    const int b0   = blockIdx.x * BGRP;
    const int ddB  = blockIdx.y * DDBLK;

    float* xs = lds;
    for (int j = tid; j < (BGRP * DDBLK) / 4; j += 256) {   // 320 float4
        int i  = j / (DDBLK / 4);
        int c4 = j % (DDBLK / 4);
        float4 v = *(const float4*)(x + (size_t)(b0 + i) * D_INNER + ddB + c4 * 4);
        *(float4*)(xs + i * DDBLK + c4 * 4) = v;
    }
    __syncthreads();

    const int dd0 = wv * 40;
    const float* p0 = Wdtlow + (size_t)(ddB + dd0) * DT_RANK + lane;
    const float* p1 = p0 + 64;
    const float* p2;
    int st2;
    if (lane < 32)      { p2 = p0 + 128;                                          st2 = DT_RANK; }
    else if (lane < 48) { p2 = WB + (size_t)(ddB + dd0) * N_STATE + (lane - 32);  st2 = N_STATE; }
    else                { p2 = WC + (size_t)(ddB + dd0) * N_STATE + (lane - 48);  st2 = N_STATE; }

    float acc0[BGRP], acc1[BGRP], acc2[BGRP];
#pragma unroll
    for (int i = 0; i < BGRP; ++i) { acc0[i] = 0.f; acc1[i] = 0.f; acc2[i] = 0.f; }

#pragma unroll 2
    for (int g = 0; g < 10; ++g) {           // 4 dd per group
        float w0[4], w1[4], w2[4];
#pragma unroll
        for (int u = 0; u < 4; ++u) {
            int dd = g * 4 + u;
            w0[u] = p0[(size_t)dd * DT_RANK];
            w1[u] = p1[(size_t)dd * DT_RANK];
            w2[u] = p2[(size_t)dd * st2];
        }
#pragma unroll
        for (int i = 0; i < BGRP; ++i) {
            float4 xv = *(const float4*)(xs + i * DDBLK + dd0 + g * 4);
            acc0[i] += xv.x * w0[0] + xv.y * w0[1] + xv.z * w0[2] + xv.w * w0[3];
            acc1[i] += xv.x * w1[0] + xv.y * w1[1] + xv.z * w1[2] + xv.w * w1[3];
            acc2[i] += xv.x * w2[0] + xv.y * w2[1] + xv.z * w2[2] + xv.w * w2[3];
        }
    }
    __syncthreads();

#pragma unroll
    for (int i = 0; i < BGRP; ++i) {
        float* r = lds + wv * (BGRP * KTOT) + i * KTOT;
        r[lane]       = acc0[i];
        r[lane + 64]  = acc1[i];
        r[lane + 128] = acc2[i];
    }
    __syncthreads();

    float* P = ws + OFF_P + (size_t)blockIdx.y * (BATCH * KTOT) + (size_t)b0 * KTOT;
#pragma unroll
    for (int r = 0; r < 6; ++r) {
        int idx = tid + r * 256;
        P[idx] = lds[idx] + lds[idx + 1536] + lds[idx + 3072] + lds[idx + 4608];
    }
}

// ---------------------------------------------------------------------------
// K2: reduce split-K partials -> T[256][192]  (unchanged, ~2 us)
// ---------------------------------------------------------------------------
__global__ __launch_bounds__(256) void k2_reduce(float* __restrict__ ws) {
    int g = blockIdx.x * 256 + threadIdx.x;    // < 49152
    const float* P = ws + OFF_P;
    float a = 0.f;
#pragma unroll
    for (int s = 0; s < SPLIT; ++s) a += P[(size_t)s * (BATCH * KTOT) + g];
    ws[OFF_T + g] = a;
}

// ---------------------------------------------------------------------------
// K3: fused delta GEMM + softplus + scan, HIGH-TLP form.
// 1-wave blocks, lane = d; 4 batches/block; grid (80,64) = 5120 blocks
// (20 blocks/CU queued -> block turnover hides per-block latency chains).
// Delta GEMM reads Wdt k-major (coalesced 256B/wave/k); T rows wave-uniform
// -> s_loads. All 16 h0 float4 prefetched into regs before exp chain (MLP=16).
// ---------------------------------------------------------------------------
__global__ __launch_bounds__(64, 4) void k3_fused(const float* __restrict__ Wdt,
                                                  const float* __restrict__ b_dt,
                                                  const float* __restrict__ x,
                                                  const float* __restrict__ A,
                                                  const float* __restrict__ Dv,
                                                  const float* __restrict__ h0,
                                                  const float* __restrict__ ws,
                                                  float* __restrict__ out) {
    const int lane = threadIdx.x;
    const int d    = blockIdx.x * 64 + lane;
    const int b0   = blockIdx.y * K3_BT;
    const float* T = ws + OFF_T;

    // ---- delta pre-activation GEMM: acc[i] = T[b0+i][0..159] . Wdt[:,d] ----
    const float* t0 = T + (size_t)(b0 + 0) * KTOT;   // wave-uniform -> s_load
    const float* t1 = T + (size_t)(b0 + 1) * KTOT;
    const float* t2 = T + (size_t)(b0 + 2) * KTOT;
    const float* t3 = T + (size_t)(b0 + 3) * KTOT;

    float acc[K3_BT] = {0.f, 0.f, 0.f, 0.f};
#pragma unroll 8
    for (int k = 0; k < DT_RANK; ++k) {
        float w = Wdt[(size_t)k * D_INNER + d];      // coalesced 256B/wave
        acc[0] += t0[k] * w;
        acc[1] += t1[k] * w;
        acc[2] += t2[k] * w;
        acc[3] += t3[k] * w;
    }

    // ---- prefetch ALL h0 fragments (16 independent b128 loads in flight) ----
    float4 h[K3_BT][4];
#pragma unroll
    for (int i = 0; i < K3_BT; ++i) {
        const float4* h4 = (const float4*)(h0 + ((size_t)(b0 + i) * D_INNER + d) * N_STATE);
        h[i][0] = h4[0]; h[i][1] = h4[1]; h[i][2] = h4[2]; h[i][3] = h4[3];
    }

    // per-d constants
    const float bdt = b_dt[d];
    const float Dd  = Dv[d];
    const float4* a4 = (const float4*)(A + (size_t)d * N_STATE);
    float4 a0 = a4[0], a1 = a4[1], a2 = a4[2], a3 = a4[3];

#pragma unroll
    for (int i = 0; i < K3_BT; ++i) {
        const int b = b0 + i;
        const float* Tb = T + (size_t)b * KTOT;      // uniform -> s_loads

        float v     = acc[i] + bdt;
        float delta = (v > 20.f) ? v : log1pf(__expf(v));

        float sbc = 0.f;
#pragma unroll
        for (int n = 0; n < N_STATE; ++n) sbc += Tb[160 + n] * Tb[176 + n];

        float y = 0.f;
        y += __expf(delta * a0.x) * h[i][0].x * Tb[176 + 0];
        y += __expf(delta * a0.y) * h[i][0].y * Tb[176 + 1];
        y += __expf(delta * a0.z) * h[i][0].z * Tb[176 + 2];
        y += __expf(delta * a0.w) * h[i][0].w * Tb[176 + 3];
        y += __expf(delta * a1.x) * h[i][1].x * Tb[176 + 4];
        y += __expf(delta * a1.y) * h[i][1].y * Tb[176 + 5];
        y += __expf(delta * a1.z) * h[i][1].z * Tb[176 + 6];
        y += __expf(delta * a1.w) * h[i][1].w * Tb[176 + 7];
        y += __expf(delta * a2.x) * h[i][2].x * Tb[176 + 8];
        y += __expf(delta * a2.y) * h[i][2].y * Tb[176 + 9];
        y += __expf(delta * a2.z) * h[i][2].z * Tb[176 + 10];
        y += __expf(delta * a2.w) * h[i][2].w * Tb[176 + 11];
        y += __expf(delta * a3.x) * h[i][3].x * Tb[176 + 12];
        y += __expf(delta * a3.y) * h[i][3].y * Tb[176 + 13];
        y += __expf(delta * a3.z) * h[i][3].z * Tb[176 + 14];
        y += __expf(delta * a3.w) * h[i][3].w * Tb[176 + 15];

        float xv = x[(size_t)b * D_INNER + d];
        out[(size_t)b * D_INNER + d] = xv * (Dd + delta * sbc) + y;
    }
}

// ---------------------------------------------------------------------------
extern "C" void kernel_launch(void* const* d_in, const int* in_sizes, int n_in,
                              void* d_out, int out_size, void* d_ws, size_t ws_size,
                              hipStream_t stream) {
    const float* x      = (const float*)d_in[0];
    const float* Wdtlow = (const float*)d_in[1];
    const float* Wdt    = (const float*)d_in[2];
    const float* bdt    = (const float*)d_in[3];
    const float* WB     = (const float*)d_in[4];
    const float* WC     = (const float*)d_in[5];
    const float* A      = (const float*)d_in[6];
    const float* Dv     = (const float*)d_in[7];
    const float* h0     = (const float*)d_in[8];
    float* ws  = (float*)d_ws;
    float* out = (float*)d_out;

    // K1: projection GEMM partials (1024 blocks, 16 waves/CU)
    hipLaunchKernelGGL(k1_gemm, dim3(NBG, NDDB), dim3(256), 0, stream,
                       x, Wdtlow, WB, WC, ws);
    // K2: reduce partials -> T[256][192]
    hipLaunchKernelGGL(k2_reduce, dim3((BATCH * KTOT) / 256), dim3(256), 0, stream, ws);
    // K3: fused delta GEMM + scan, 1-wave blocks, 5120 blocks (20/CU queued)
    hipLaunchKernelGGL(k3_fused, dim3(D_INNER / 64, BATCH / K3_BT), dim3(64),
                       0, stream, Wdt, bdt, x, A, Dv, h0, ws, out);
}

// Round 9
// 175.537 us; speedup vs baseline: 1.0465x; 1.0465x over previous
//
#include <hip/hip_runtime.h>
#include <math.h>

#define D_INNER 5120
#define DT_RANK 160
#define N_STATE 16
#define BATCH   256
#define KTOT    192               // 160 (dt_low) | 16 (B) | 16 (C)

// ---- K1 config: 256-thr blocks, 4 waves x 40-dd chunks, intra-block reduce ----
#define BGRP    8                 // batches per block
#define NBG     (BATCH / BGRP)    // 32
#define DDBLK   160               // dd per block (4 waves x 40)
#define NDDB    (D_INNER / DDBLK) // 32 -> SPLIT partials
#define SPLIT   32

// ---- K3 config: 256-thr blocks, 4 batches/block, grid (20,64)=1280 blocks ----
#define K3_BT   4

// ---- workspace layout (float offsets) ----
#define OFF_T     0
#define SZ_T      (BATCH * KTOT)                  // 49,152
#define OFF_P     (OFF_T + SZ_T)
#define SZ_P      (SPLIT * BATCH * KTOT)          // 1,572,864 (6.3 MB)

// ---------------------------------------------------------------------------
// K1: projection GEMM partials (unchanged, ~10 us).
// ---------------------------------------------------------------------------
__global__ __launch_bounds__(256) void k1_gemm(const float* __restrict__ x,
                                               const float* __restrict__ Wdtlow,
                                               const float* __restrict__ WB,
                                               const float* __restrict__ WC,
                                               float* __restrict__ ws) {
    __shared__ float lds[4 * BGRP * KTOT];   // 6144 floats = 24 KB
    const int tid  = threadIdx.x;
    const int lane = tid & 63;
    const int wv   = tid >> 6;               // wave 0..3
    const int b0   = blockIdx.x * BGRP;
    const int ddB  = blockIdx.y * DDBLK;

    float* xs = lds;
    for (int j = tid; j < (BGRP * DDBLK) / 4; j += 256) {   // 320 float4
        int i  = j / (DDBLK / 4);
        int c4 = j % (DDBLK / 4);
        float4 v = *(const float4*)(x + (size_t)(b0 + i) * D_INNER + ddB + c4 * 4);
        *(float4*)(xs + i * DDBLK + c4 * 4) = v;
    }
    __syncthreads();

    const int dd0 = wv * 40;
    const float* p0 = Wdtlow + (size_t)(ddB + dd0) * DT_RANK + lane;
    const float* p1 = p0 + 64;
    const float* p2;
    int st2;
    if (lane < 32)      { p2 = p0 + 128;                                          st2 = DT_RANK; }
    else if (lane < 48) { p2 = WB + (size_t)(ddB + dd0) * N_STATE + (lane - 32);  st2 = N_STATE; }
    else                { p2 = WC + (size_t)(ddB + dd0) * N_STATE + (lane - 48);  st2 = N_STATE; }

    float acc0[BGRP], acc1[BGRP], acc2[BGRP];
#pragma unroll
    for (int i = 0; i < BGRP; ++i) { acc0[i] = 0.f; acc1[i] = 0.f; acc2[i] = 0.f; }

#pragma unroll 2
    for (int g = 0; g < 10; ++g) {           // 4 dd per group
        float w0[4], w1[4], w2[4];
#pragma unroll
        for (int u = 0; u < 4; ++u) {
            int dd = g * 4 + u;
            w0[u] = p0[(size_t)dd * DT_RANK];
            w1[u] = p1[(size_t)dd * DT_RANK];
            w2[u] = p2[(size_t)dd * st2];
        }
#pragma unroll
        for (int i = 0; i < BGRP; ++i) {
            float4 xv = *(const float4*)(xs + i * DDBLK + dd0 + g * 4);
            acc0[i] += xv.x * w0[0] + xv.y * w0[1] + xv.z * w0[2] + xv.w * w0[3];
            acc1[i] += xv.x * w1[0] + xv.y * w1[1] + xv.z * w1[2] + xv.w * w1[3];
            acc2[i] += xv.x * w2[0] + xv.y * w2[1] + xv.z * w2[2] + xv.w * w2[3];
        }
    }
    __syncthreads();

#pragma unroll
    for (int i = 0; i < BGRP; ++i) {
        float* r = lds + wv * (BGRP * KTOT) + i * KTOT;
        r[lane]       = acc0[i];
        r[lane + 64]  = acc1[i];
        r[lane + 128] = acc2[i];
    }
    __syncthreads();

    float* P = ws + OFF_P + (size_t)blockIdx.y * (BATCH * KTOT) + (size_t)b0 * KTOT;
#pragma unroll
    for (int r = 0; r < 6; ++r) {
        int idx = tid + r * 256;
        P[idx] = lds[idx] + lds[idx + 1536] + lds[idx + 3072] + lds[idx + 4608];
    }
}

// ---------------------------------------------------------------------------
// K2: reduce split-K partials -> T[256][192]  (unchanged, ~2 us)
// ---------------------------------------------------------------------------
__global__ __launch_bounds__(256) void k2_reduce(float* __restrict__ ws) {
    int g = blockIdx.x * 256 + threadIdx.x;    // < 49152
    const float* P = ws + OFF_P;
    float a = 0.f;
#pragma unroll
    for (int s = 0; s < SPLIT; ++s) a += P[(size_t)s * (BATCH * KTOT) + g];
    ws[OFF_T + g] = a;
}

// ---------------------------------------------------------------------------
// K3: fused delta GEMM + softplus + scan — HIGH OCCUPANCY + pipelined MLP.
// 256-thr blocks, thread owns d, 4 batches; grid (20,64) = 1280 blocks.
// __launch_bounds__(256,6) caps VGPR (~85) -> ~24 waves/CU resident.
// h0 reads are 2-deep software-pipelined: h[i+1] issues before h[i] is
// consumed (in-order vmcnt => true overlap). T rows wave-uniform -> s_loads;
// Wdt k-major coalesced.
// ---------------------------------------------------------------------------
__global__ __launch_bounds__(256, 6) void k3_fused(const float* __restrict__ Wdt,
                                                   const float* __restrict__ b_dt,
                                                   const float* __restrict__ x,
                                                   const float* __restrict__ A,
                                                   const float* __restrict__ Dv,
                                                   const float* __restrict__ h0,
                                                   const float* __restrict__ ws,
                                                   float* __restrict__ out) {
    const int tid = threadIdx.x;
    const int d   = blockIdx.x * 256 + tid;
    const int b0  = blockIdx.y * K3_BT;
    const float* T = ws + OFF_T;

    // ---- delta pre-activation GEMM: acc[i] = T[b0+i][0..159] . Wdt[:,d] ----
    const float* t0 = T + (size_t)(b0 + 0) * KTOT;   // wave-uniform -> s_load
    const float* t1 = T + (size_t)(b0 + 1) * KTOT;
    const float* t2 = T + (size_t)(b0 + 2) * KTOT;
    const float* t3 = T + (size_t)(b0 + 3) * KTOT;

    float acc[K3_BT] = {0.f, 0.f, 0.f, 0.f};
#pragma unroll 8
    for (int k = 0; k < DT_RANK; ++k) {
        float w = Wdt[(size_t)k * D_INNER + d];      // coalesced 1KB/wave
        acc[0] += t0[k] * w;
        acc[1] += t1[k] * w;
        acc[2] += t2[k] * w;
        acc[3] += t3[k] * w;
    }

    // per-d constants
    const float bdt = b_dt[d];
    const float Dd  = Dv[d];
    const float4* a4 = (const float4*)(A + (size_t)d * N_STATE);
    float4 a0 = a4[0], a1 = a4[1], a2 = a4[2], a3 = a4[3];

    // ---- software-pipelined scan over 4 batches ----
    const float4* hb = (const float4*)(h0 + ((size_t)b0 * D_INNER + d) * N_STATE);
    const size_t  hstride = (size_t)D_INNER * 4;     // float4s per batch step

    float4 hc0 = hb[0], hc1 = hb[1], hc2 = hb[2], hc3 = hb[3];

#pragma unroll
    for (int i = 0; i < K3_BT; ++i) {
        float4 hn0, hn1, hn2, hn3;
        if (i < K3_BT - 1) {                          // prefetch next batch
            const float4* hn = hb + (size_t)(i + 1) * hstride;
            hn0 = hn[0]; hn1 = hn[1]; hn2 = hn[2]; hn3 = hn[3];
        }

        const int b = b0 + i;
        const float* Tb = T + (size_t)b * KTOT;       // uniform -> s_loads

        float v     = acc[i] + bdt;
        float delta = (v > 20.f) ? v : log1pf(__expf(v));

        float sbc = 0.f;
#pragma unroll
        for (int n = 0; n < N_STATE; ++n) sbc += Tb[160 + n] * Tb[176 + n];

        float y = 0.f;
        y += __expf(delta * a0.x) * hc0.x * Tb[176 + 0];
        y += __expf(delta * a0.y) * hc0.y * Tb[176 + 1];
        y += __expf(delta * a0.z) * hc0.z * Tb[176 + 2];
        y += __expf(delta * a0.w) * hc0.w * Tb[176 + 3];
        y += __expf(delta * a1.x) * hc1.x * Tb[176 + 4];
        y += __expf(delta * a1.y) * hc1.y * Tb[176 + 5];
        y += __expf(delta * a1.z) * hc1.z * Tb[176 + 6];
        y += __expf(delta * a1.w) * hc1.w * Tb[176 + 7];
        y += __expf(delta * a2.x) * hc2.x * Tb[176 + 8];
        y += __expf(delta * a2.y) * hc2.y * Tb[176 + 9];
        y += __expf(delta * a2.z) * hc2.z * Tb[176 + 10];
        y += __expf(delta * a2.w) * hc2.w * Tb[176 + 11];
        y += __expf(delta * a3.x) * hc3.x * Tb[176 + 12];
        y += __expf(delta * a3.y) * hc3.y * Tb[176 + 13];
        y += __expf(delta * a3.z) * hc3.z * Tb[176 + 14];
        y += __expf(delta * a3.w) * hc3.w * Tb[176 + 15];

        float xv = x[(size_t)b * D_INNER + d];
        out[(size_t)b * D_INNER + d] = xv * (Dd + delta * sbc) + y;

        if (i < K3_BT - 1) { hc0 = hn0; hc1 = hn1; hc2 = hn2; hc3 = hn3; }
    }
}

// ---------------------------------------------------------------------------
extern "C" void kernel_launch(void* const* d_in, const int* in_sizes, int n_in,
                              void* d_out, int out_size, void* d_ws, size_t ws_size,
                              hipStream_t stream) {
    const float* x      = (const float*)d_in[0];
    const float* Wdtlow = (const float*)d_in[1];
    const float* Wdt    = (const float*)d_in[2];
    const float* bdt    = (const float*)d_in[3];
    const float* WB     = (const float*)d_in[4];
    const float* WC     = (const float*)d_in[5];
    const float* A      = (const float*)d_in[6];
    const float* Dv     = (const float*)d_in[7];
    const float* h0     = (const float*)d_in[8];
    float* ws  = (float*)d_ws;
    float* out = (float*)d_out;

    // K1: projection GEMM partials (1024 blocks, 16 waves/CU)
    hipLaunchKernelGGL(k1_gemm, dim3(NBG, NDDB), dim3(256), 0, stream,
                       x, Wdtlow, WB, WC, ws);
    // K2: reduce partials -> T[256][192]
    hipLaunchKernelGGL(k2_reduce, dim3((BATCH * KTOT) / 256), dim3(256), 0, stream, ws);
    // K3: fused delta GEMM + scan, 256-thr blocks, high occupancy + pipeline
    hipLaunchKernelGGL(k3_fused, dim3(D_INNER / 256, BATCH / K3_BT), dim3(256),
                       0, stream, Wdt, bdt, x, A, Dv, h0, ws, out);
}